// Round 17
// baseline (75.876 us; speedup 1.0000x reference)
//
#include <hip/hip_runtime.h>
#include <hip/hip_bf16.h>
#include <math.h>

#define B_ 8
#define T_ 256
#define LQ_ 20
#define LC_ 10
#define DIM_ 128
#define N_ 257            // T+1
#define NN_ (B_*N_)       // 2056

typedef __attribute__((ext_vector_type(8))) short bf16x8;   // 8 bf16 (4 VGPRs)
typedef __attribute__((ext_vector_type(4))) float f32x4;

__device__ __forceinline__ unsigned short f2bf(float f) {
  unsigned u = __float_as_uint(f);
  unsigned r = u + 0x7FFFu + ((u >> 16) & 1u);   // round-to-nearest-even
  return (unsigned short)(r >> 16);
}
__device__ __forceinline__ float bf2f(unsigned short h) {
  return __uint_as_float(((unsigned)h) << 16);
}

// ---------------- kPRE: queries -> eq  ∪  weight transpose+convert -----------
// blocks 0..159: query rows. 160..223: Wv (KD=1024, 16 k-rows each).
// 224..263: {We,Wq,Wk,Wvv,Ws} (KD=128, 8 blocks x 16 k-rows each).
__global__ __launch_bounds__(256) void kPRE(
    const int* __restrict__ word_ids, const int* __restrict__ char_ids,
    const float* __restrict__ word_emb, const float* __restrict__ char_emb,
    const float* __restrict__ W_embed, const float* __restrict__ b_embed,
    const float* __restrict__ We, const float* __restrict__ be,
    const float* __restrict__ q_mask,
    const float* __restrict__ Wv,
    const float* __restrict__ Wq, const float* __restrict__ Wk,
    const float* __restrict__ Wvv, const float* __restrict__ Ws,
    float* __restrict__ eq,
    unsigned short* __restrict__ WvTh, unsigned short* __restrict__ WvTl,
    unsigned short* __restrict__ WcH, unsigned short* __restrict__ WcL)
{
  __shared__ __align__(16) float smem[2112];
  const int blk = blockIdx.x, tid = threadIdx.x;
  if (blk < 160) {
    const int qi = blk;
    const int b = qi / 20, lq = qi - b * 20;
    float* emb = smem;            // [352]
    float* ps  = emb + 352;       // [2][128]
    float* hq  = emb + 608;       // [128]
    float* pe  = emb + 736;       // [2][128]
    const int wid = word_ids[b * LQ_ + lq];
    for (int m2 = tid; m2 < 300; m2 += 256) emb[m2] = word_emb[(size_t)wid * 300 + m2];
    if (tid < 50) {
      float s = 0.f;
      #pragma unroll
      for (int l = 0; l < 10; ++l) {
        const int cid = char_ids[(b * LQ_ + lq) * 10 + l];
        s += char_emb[cid * 50 + tid];
      }
      emb[300 + tid] = s * 0.1f;
    }
    __syncthreads();
    const int j = tid & 127, half = tid >> 7;
    {
      float a = 0.f;
      const float* Wcol = W_embed + (size_t)(half * 175) * 128 + j;
      const float* eh = emb + half * 175;
      #pragma unroll 5
      for (int m2 = 0; m2 < 175; ++m2) a += eh[m2] * Wcol[(size_t)m2 * 128];
      ps[half * 128 + j] = a;
    }
    __syncthreads();
    if (tid < 128) hq[tid] = ps[tid] + ps[128 + tid] + b_embed[tid];
    __syncthreads();
    {
      float e = 0.f;
      #pragma unroll 8
      for (int kk = 0; kk < 64; ++kk)
        e += hq[half * 64 + kk] * We[(half * 64 + kk) * 128 + j];
      pe[half * 128 + j] = e;
    }
    __syncthreads();
    if (tid < 128) {
      float ev = pe[tid] + pe[128 + tid] + be[tid];
      ev = fmaxf(ev, 0.f) * q_mask[b * LQ_ + lq];
      eq[(size_t)qi * 128 + tid] = ev;
    }
  } else {
    // generic transpose+convert of 16 k-rows of a [K][128] matrix
    const float* src; unsigned short *dh, *dl; int k0, KD;
    int cb = blk - 160;
    if (cb < 64) { k0 = cb * 16; KD = 1024; src = Wv + (size_t)k0 * 128; dh = WvTh; dl = WvTl; }
    else {
      cb -= 64;
      const int m = cb >> 3, kr = cb & 7;
      const float* Wmat[5] = {We, Wq, Wk, Wvv, Ws};
      k0 = kr * 16; KD = 128;
      src = Wmat[m] + (size_t)k0 * 128;
      dh = WcH + (size_t)m * 16384; dl = WcL + (size_t)m * 16384;
    }
    const float4* s4 = reinterpret_cast<const float4*>(src);
    #pragma unroll
    for (int i = 0; i < 2; ++i) {
      const int idx4 = tid + i * 256;
      const int r = idx4 >> 5, f = idx4 & 31;
      *reinterpret_cast<float4*>(&smem[r * 132 + f * 4]) = s4[r * 32 + f];
    }
    __syncthreads();
    const int col = tid & 127, kg = tid >> 7;     // kg 0..1
    bf16x8 vh, vl;
    #pragma unroll
    for (int j = 0; j < 8; ++j) {
      const int kk = kg * 8 + j;
      const float xv = smem[kk * 132 + col];
      const unsigned short hi = f2bf(xv);
      const unsigned short lo = f2bf(xv - bf2f(hi));
      vh[j] = (short)hi; vl[j] = (short)lo;
    }
    *reinterpret_cast<bf16x8*>(dh + (size_t)col * KD + k0 + kg * 8) = vh;
    *reinterpret_cast<bf16x8*>(dl + (size_t)col * KD + k0 + kg * 8) = vl;
  }
}

// ---------------- kNMF: all-MFMA node pipeline (video+enc+proj) --------------
// 128 blocks x 512 thr (8 waves); 16 rows/block, full K=1024.
// Conventions HW-verified in R16: A row=lane&15,k=(lane>>4)*8+j;
// C col=lane&15,row=(lane>>4)*4+reg. Split-bf16: hh+hl+lh.
__global__ __launch_bounds__(512) void kNMF(
    const float* __restrict__ video,
    const unsigned short* __restrict__ WvTh, const unsigned short* __restrict__ WvTl,
    const unsigned short* __restrict__ WcH, const unsigned short* __restrict__ WcL,
    const float* __restrict__ bvp, const float* __restrict__ be,
    const float* __restrict__ vmask,
    const float* __restrict__ bq, const float* __restrict__ bk,
    const float* __restrict__ bval, const float* __restrict__ bs,
    float* __restrict__ q, float* __restrict__ k,
    float* __restrict__ v, float* __restrict__ sk)
{
  __shared__ __align__(16) unsigned short Abuf[32 * 1024];  // 64 KB: Ah | Al
  char* Ahb = reinterpret_cast<char*>(Abuf);
  char* Alb = Ahb + 32768;
  float* hl = reinterpret_cast<float*>(Abuf);          // [16][132] after A dead
  float* xe = hl + 2112;                               // [16][132]
  const int blk = blockIdx.x, tid = threadIdx.x;
  const int r0 = blk * 16;
  const float* bm[4] = {bq, bk, bval, bs};
  float* om[4] = {q, k, v, sk};

  // ---- stage video 16x1024 -> bf16 hi/lo, swizzled ----
  #pragma unroll
  for (int i = 0; i < 4; ++i) {
    const int g = i * 512 + tid;
    const int row = g >> 7, gk = g & 127;
    const float* src = video + (size_t)(r0 + row) * 1024 + gk * 8;
    const float4 x0 = *reinterpret_cast<const float4*>(src);
    const float4 x1 = *reinterpret_cast<const float4*>(src + 4);
    const float xs[8] = {x0.x, x0.y, x0.z, x0.w, x1.x, x1.y, x1.z, x1.w};
    bf16x8 vh, vl;
    #pragma unroll
    for (int j = 0; j < 8; ++j) {
      const unsigned short hi = f2bf(xs[j]);
      const unsigned short lo = f2bf(xs[j] - bf2f(hi));
      vh[j] = (short)hi; vl[j] = (short)lo;
    }
    const int byteoff = (row * 2048 + gk * 16) ^ ((row & 7) << 4);
    *reinterpret_cast<bf16x8*>(Ahb + byteoff) = vh;
    *reinterpret_cast<bf16x8*>(Alb + byteoff) = vl;
  }
  __syncthreads();

  const int wv = tid >> 6, lane = tid & 63;
  const int col16 = lane & 15, kg8 = lane >> 4;
  const int c0 = wv * 16;
  const int arow = lane & 15;
  const int ocol = c0 + col16;
  const int orow = (lane >> 4) * 4;

  // ---- phase B: video @ Wv (K=1024), 96 MFMA ----
  f32x4 acc = {0.f, 0.f, 0.f, 0.f};
  {
    const unsigned short* pBh = WvTh + (size_t)ocol * 1024;
    const unsigned short* pBl = WvTl + (size_t)ocol * 1024;
    #pragma unroll 4
    for (int t = 0; t < 32; ++t) {
      const int kb = t * 32 + kg8 * 8;
      const int aoff = (arow * 2048 + kb * 2) ^ ((arow & 7) << 4);
      const bf16x8 ah = *reinterpret_cast<const bf16x8*>(Ahb + aoff);
      const bf16x8 al = *reinterpret_cast<const bf16x8*>(Alb + aoff);
      const bf16x8 bh = *reinterpret_cast<const bf16x8*>(pBh + kb);
      const bf16x8 bl = *reinterpret_cast<const bf16x8*>(pBl + kb);
      acc = __builtin_amdgcn_mfma_f32_16x16x32_bf16(ah, bh, acc, 0, 0, 0);
      acc = __builtin_amdgcn_mfma_f32_16x16x32_bf16(ah, bl, acc, 0, 0, 0);
      acc = __builtin_amdgcn_mfma_f32_16x16x32_bf16(al, bh, acc, 0, 0, 0);
    }
  }
  __syncthreads();                       // all A reads done -> reuse as hl/xe
  {
    const float bv = bvp[ocol];
    #pragma unroll
    for (int i = 0; i < 4; ++i) hl[(orow + i) * 132 + ocol] = acc[i] + bv;
  }
  __syncthreads();

  // ---- phase C: enc = relu(h @ We + be) * mask, 12 MFMA ----
  bf16x8 ahE[4], alE[4];
  #pragma unroll
  for (int t = 0; t < 4; ++t) {
    const int kbase = t * 32 + kg8 * 8;
    const float4 f0 = *reinterpret_cast<const float4*>(&hl[arow * 132 + kbase]);
    const float4 f1 = *reinterpret_cast<const float4*>(&hl[arow * 132 + kbase + 4]);
    const float fs[8] = {f0.x, f0.y, f0.z, f0.w, f1.x, f1.y, f1.z, f1.w};
    #pragma unroll
    for (int j = 0; j < 8; ++j) {
      const unsigned short hi = f2bf(fs[j]);
      const unsigned short lo = f2bf(fs[j] - bf2f(hi));
      ahE[t][j] = (short)hi; alE[t][j] = (short)lo;
    }
  }
  acc = f32x4{0.f, 0.f, 0.f, 0.f};
  {
    const unsigned short* pBh = WcH + (size_t)ocol * 128;   // We at offset 0
    const unsigned short* pBl = WcL + (size_t)ocol * 128;
    #pragma unroll
    for (int t = 0; t < 4; ++t) {
      const int kb = t * 32 + kg8 * 8;
      const bf16x8 bh = *reinterpret_cast<const bf16x8*>(pBh + kb);
      const bf16x8 bl = *reinterpret_cast<const bf16x8*>(pBl + kb);
      acc = __builtin_amdgcn_mfma_f32_16x16x32_bf16(ahE[t], bh, acc, 0, 0, 0);
      acc = __builtin_amdgcn_mfma_f32_16x16x32_bf16(ahE[t], bl, acc, 0, 0, 0);
      acc = __builtin_amdgcn_mfma_f32_16x16x32_bf16(alE[t], bh, acc, 0, 0, 0);
    }
  }
  __syncthreads();                       // hl reads done before xe region reuse? xe disjoint; order writes
  {
    const float bev = be[ocol];
    #pragma unroll
    for (int i = 0; i < 4; ++i) {
      float xv = acc[i] + bev;
      xv = fmaxf(xv, 0.f) * vmask[r0 + orow + i];
      xe[(orow + i) * 132 + ocol] = xv;
    }
  }
  __syncthreads();

  // ---- phase D: 4 projections, wave = (matrix m, col-half ch), 48 MFMA ----
  const int m = wv >> 1, ch = wv & 1;
  bf16x8 ahP[4], alP[4];
  #pragma unroll
  for (int t = 0; t < 4; ++t) {
    const int kbase = t * 32 + kg8 * 8;
    const float4 f0 = *reinterpret_cast<const float4*>(&xe[arow * 132 + kbase]);
    const float4 f1 = *reinterpret_cast<const float4*>(&xe[arow * 132 + kbase + 4]);
    const float fs[8] = {f0.x, f0.y, f0.z, f0.w, f1.x, f1.y, f1.z, f1.w};
    #pragma unroll
    for (int j = 0; j < 8; ++j) {
      const unsigned short hi = f2bf(fs[j]);
      const unsigned short lo = f2bf(fs[j] - bf2f(hi));
      ahP[t][j] = (short)hi; alP[t][j] = (short)lo;
    }
  }
  const unsigned short* WmH = WcH + (size_t)(1 + m) * 16384;
  const unsigned short* WmL = WcL + (size_t)(1 + m) * 16384;
  #pragma unroll
  for (int tt = 0; tt < 4; ++tt) {
    const int cc0 = ch * 64 + tt * 16;
    const int occ = cc0 + col16;
    const unsigned short* pBh = WmH + (size_t)occ * 128;
    const unsigned short* pBl = WmL + (size_t)occ * 128;
    f32x4 ac2 = {0.f, 0.f, 0.f, 0.f};
    #pragma unroll
    for (int t = 0; t < 4; ++t) {
      const int kb = t * 32 + kg8 * 8;
      const bf16x8 bh = *reinterpret_cast<const bf16x8*>(pBh + kb);
      const bf16x8 bl = *reinterpret_cast<const bf16x8*>(pBl + kb);
      ac2 = __builtin_amdgcn_mfma_f32_16x16x32_bf16(ahP[t], bh, ac2, 0, 0, 0);
      ac2 = __builtin_amdgcn_mfma_f32_16x16x32_bf16(ahP[t], bl, ac2, 0, 0, 0);
      ac2 = __builtin_amdgcn_mfma_f32_16x16x32_bf16(alP[t], bh, ac2, 0, 0, 0);
    }
    const float bb = bm[m][occ];
    #pragma unroll
    for (int i = 0; i < 4; ++i) {
      const int vr = r0 + orow + i;
      const int node = (vr >> 8) * 257 + 1 + (vr & 255);
      om[m][(size_t)node * 128 + occ] = ac2[i] + bb;
    }
  }
}

// ---------------- edge multiplicity (verified round 1) -----------------------
__device__ __forceinline__ float cntf(int dnode, int s) {
  if (dnode == 256) return (s == 0 ? 1.f : 0.f) + (s == 255 ? 1.f : 0.f);
  float c = (s != dnode) ? 1.f : 0.f;          // semantic all-pairs (nodes 0..255)
  if (s == 0) c += 1.f;                        // query->segment
  if (s == dnode - 1) c += 2.f;                // qe chain + temporal h=1 fwd
  if (s == dnode + 1 && dnode <= 254) c += 1.f;// temporal h=1 bwd
  if (s == dnode - 2 && dnode >= 2) c += 1.f;  // temporal h=2 fwd
  if (s == dnode + 2 && dnode <= 253) c += 1.f;// temporal h=2 bwd
  return c;
}

// ---------------- kATTN: single-pass fused exp+PV (proven shape) -------------
__global__ __launch_bounds__(256) void kATTN(
    const float* __restrict__ q, const float* __restrict__ k,
    const float* __restrict__ v, const float* __restrict__ eq,
    const float* __restrict__ Wk, const float* __restrict__ bk,
    const float* __restrict__ Wvv, const float* __restrict__ bval,
    float* __restrict__ npart, float* __restrict__ dpart)
{
  __shared__ float Kl[32][128];
  __shared__ float Vl[32][128];
  __shared__ float m0[128];
  const int d0 = blockIdx.x * 32;
  const int y  = blockIdx.y;
  const int b  = blockIdx.z;
  const int tid = threadIdx.x;
  const int base = b * 257;
  const int s0 = y * 32;
  {
    const float4* ksrc = reinterpret_cast<const float4*>(k + (size_t)(base + s0) * 128);
    const float4* vsrc = reinterpret_cast<const float4*>(v + (size_t)(base + s0) * 128);
    float4* kd = reinterpret_cast<float4*>(Kl);
    float4* vd = reinterpret_cast<float4*>(Vl);
    #pragma unroll
    for (int i = 0; i < 4; ++i) {
      kd[tid + i * 256] = ksrc[tid + i * 256];
      vd[tid + i * 256] = vsrc[tid + i * 256];
    }
  }
  if (y == 0 && tid < 128) {
    float s = 0.f;
    #pragma unroll 4
    for (int lq = 0; lq < LQ_; ++lq) s += eq[((size_t)b * LQ_ + lq) * 128 + tid];
    m0[tid] = s * (1.f / LQ_);
  }
  const int dd = tid >> 3, h = tid & 7;
  const int dnode = d0 + dd + 1;
  const float* qrow = q + (size_t)(base + dnode) * 128 + h * 16;
  const float4 qq0 = *(const float4*)(qrow + 0);
  const float4 qq1 = *(const float4*)(qrow + 4);
  const float4 qq2 = *(const float4*)(qrow + 8);
  const float4 qq3 = *(const float4*)(qrow + 12);
  __syncthreads();
  if (y == 0) {                        // overwrite row 0 with node-0 K/V
    const int j = tid & 127, half = tid >> 7;
    const float* W = half ? Wvv : Wk;
    float acc = half ? bval[j] : bk[j];
    #pragma unroll 8
    for (int kk = 0; kk < 128; ++kk) acc += m0[kk] * W[kk * 128 + j];
    if (half) Vl[0][j] = acc; else Kl[0][j] = acc;
  }
  __syncthreads();

  float den = 0.f;
  float4 o0 = {0,0,0,0}, o1 = {0,0,0,0}, o2 = {0,0,0,0}, o3 = {0,0,0,0};
  #pragma unroll 2
  for (int s = 0; s < 32; ++s) {
    const float* krow = &Kl[s][h * 16];
    const float4 k0 = *(const float4*)(krow + 0);
    const float4 k1 = *(const float4*)(krow + 4);
    const float4 k2 = *(const float4*)(krow + 8);
    const float4 k3 = *(const float4*)(krow + 12);
    float dt = qq0.x*k0.x + qq0.y*k0.y + qq0.z*k0.z + qq0.w*k0.w
             + qq1.x*k1.x + qq1.y*k1.y + qq1.z*k1.z + qq1.w*k1.w
             + qq2.x*k2.x + qq2.y*k2.y + qq2.z*k2.z + qq2.w*k2.w
             + qq3.x*k3.x + qq3.y*k3.y + qq3.z*k3.z + qq3.w*k3.w;
    const float c = cntf(dnode, s0 + s);
    const float pw = c * __expf(dt * 0.25f);
    den += pw;
    const float* vrow = &Vl[s][h * 16];
    const float4 v0 = *(const float4*)(vrow + 0);
    const float4 v1 = *(const float4*)(vrow + 4);
    const float4 v2 = *(const float4*)(vrow + 8);
    const float4 v3 = *(const float4*)(vrow + 12);
    o0.x += pw*v0.x; o0.y += pw*v0.y; o0.z += pw*v0.z; o0.w += pw*v0.w;
    o1.x += pw*v1.x; o1.y += pw*v1.y; o1.z += pw*v1.z; o1.w += pw*v1.w;
    o2.x += pw*v2.x; o2.y += pw*v2.y; o2.z += pw*v2.z; o2.w += pw*v2.w;
    o3.x += pw*v3.x; o3.y += pw*v3.y; o3.z += pw*v3.z; o3.w += pw*v3.w;
  }
  const size_t pb = ((size_t)y * 8 + b) * 256 + d0;
  float* np = npart + (pb + dd) * 128 + h * 16;
  *reinterpret_cast<float4*>(np + 0)  = o0;
  *reinterpret_cast<float4*>(np + 4)  = o1;
  *reinterpret_cast<float4*>(np + 8)  = o2;
  *reinterpret_cast<float4*>(np + 12) = o3;
  dpart[(pb + dd) * 8 + h] = den;
}

// ---------------- kRED: combine 8 partials + skip + start/end logits ---------
__global__ __launch_bounds__(256) void kRED(
    const float* __restrict__ npart, const float* __restrict__ dpart,
    const float* __restrict__ sk,
    const float* __restrict__ W_start, const float* __restrict__ b_start,
    const float* __restrict__ W_end, const float* __restrict__ b_end,
    float* __restrict__ out)
{
  __shared__ float red[16][2][2];
  const int d0 = blockIdx.x * 16;
  const int b = blockIdx.y;
  const int tid = threadIdx.x;
  const int base = b * 257;
  const int jB = tid & 127, shB = tid >> 7;
  const int hB = jB >> 4;
  const float wst = W_start[jB], wen = W_end[jB];
  #pragma unroll
  for (int dd8 = 0; dd8 < 8; ++dd8) {
    const int dd = shB * 8 + dd8;
    const int dst = d0 + dd;
    float num = 0.f, den = 0.f;
    #pragma unroll
    for (int y = 0; y < 8; ++y) {
      const size_t pb = ((size_t)y * 8 + b) * 256 + dst;
      num += npart[pb * 128 + jB];
      den += dpart[pb * 8 + hB];
    }
    const float o = num / (den + 1e-16f) + sk[(size_t)(base + dst + 1) * 128 + jB];
    float psum = o * wst, pesum = o * wen;
    #pragma unroll
    for (int off = 1; off < 64; off <<= 1) {
      psum += __shfl_xor(psum, off);
      pesum += __shfl_xor(pesum, off);
    }
    if ((tid & 63) == 0) { red[dd][jB >> 6][0] = psum; red[dd][jB >> 6][1] = pesum; }
  }
  __syncthreads();
  if (tid < 16) {
    out[b * 256 + d0 + tid]        = red[tid][0][0] + red[tid][1][0] + b_start[0];
    out[2048 + b * 256 + d0 + tid] = red[tid][0][1] + red[tid][1][1] + b_end[0];
  }
}

extern "C" void kernel_launch(void* const* d_in, const int* in_sizes, int n_in,
                              void* d_out, int out_size, void* d_ws, size_t ws_size,
                              hipStream_t stream) {
  const int*   word_ids = (const int*)d_in[0];
  const int*   char_ids = (const int*)d_in[1];
  const float* video    = (const float*)d_in[2];
  const float* v_mask   = (const float*)d_in[3];
  const float* q_mask   = (const float*)d_in[4];
  const float* word_emb = (const float*)d_in[5];
  const float* char_emb = (const float*)d_in[6];
  const float* W_embed  = (const float*)d_in[7];
  const float* b_embed  = (const float*)d_in[8];
  const float* W_vproj  = (const float*)d_in[9];
  const float* b_vproj  = (const float*)d_in[10];
  const float* W_enc    = (const float*)d_in[11];
  const float* b_enc    = (const float*)d_in[12];
  const float* Wq       = (const float*)d_in[13];
  const float* bq       = (const float*)d_in[14];
  const float* Wk       = (const float*)d_in[15];
  const float* bk       = (const float*)d_in[16];
  const float* Wv       = (const float*)d_in[17];
  const float* bv       = (const float*)d_in[18];
  const float* Wskip    = (const float*)d_in[19];
  const float* bskip    = (const float*)d_in[20];
  const float* W_start  = (const float*)d_in[21];
  const float* b_start  = (const float*)d_in[22];
  const float* W_end    = (const float*)d_in[23];
  const float* b_end    = (const float*)d_in[24];

  float* q     = (float*)d_ws;
  float* k     = q  + NN_ * DIM_;
  float* v     = k  + NN_ * DIM_;
  float* sk    = v  + NN_ * DIM_;
  float* eq    = sk + NN_ * DIM_;                    // 160*128
  float* npart = eq + 160 * 128;                     // 8*8*256*128
  float* dpart = npart + (size_t)8 * 8 * 256 * 128;  // 8*8*256*8
  unsigned short* WvTh = (unsigned short*)(dpart + 16384);
  unsigned short* WvTl = WvTh + 131072;              // 128*1024
  unsigned short* WcH  = WvTl + 131072;              // 5*128*128
  unsigned short* WcL  = WcH + 5 * 16384;

  hipLaunchKernelGGL(kPRE, dim3(264), dim3(256), 0, stream,
    word_ids, char_ids, word_emb, char_emb, W_embed, b_embed,
    W_enc, b_enc, q_mask, W_vproj, Wq, Wk, Wv, Wskip,
    eq, WvTh, WvTl, WcH, WcL);
  hipLaunchKernelGGL(kNMF, dim3(128), dim3(512), 0, stream,
    video, WvTh, WvTl, WcH, WcL, b_vproj, b_enc, v_mask,
    bq, bk, bv, bskip, q, k, v, sk);
  hipLaunchKernelGGL(kATTN, dim3(8, 8, 8), dim3(256), 0, stream,
    q, k, v, eq, Wk, bk, Wv, bv, npart, dpart);
  hipLaunchKernelGGL(kRED, dim3(16, 8), dim3(256), 0, stream,
    npart, dpart, sk, W_start, b_start, W_end, b_end, (float*)d_out);
}

// Round 18
// 62.876 us; speedup vs baseline: 1.2068x; 1.2068x over previous
//
#include <hip/hip_runtime.h>
#include <hip/hip_bf16.h>
#include <math.h>

#define B_ 8
#define T_ 256
#define LQ_ 20
#define LC_ 10
#define DIM_ 128
#define N_ 257            // T+1
#define NN_ (B_*N_)       // 2056

// NOTE: parameter must NOT be named 'w'/'x'/'y'/'z' (R12 preprocessor trap).
#define FMA4(a, s, ww) { (a).x += (s)*(ww).x; (a).y += (s)*(ww).y; (a).z += (s)*(ww).z; (a).w += (s)*(ww).w; }

// ---------------- kNODE: R13 base + block-staggered W access -----------------
// 512 thr. Thread = (c4 0..31, ks 0..15); owns all 8 rows -> 32 FMA per
// 16B W-load; W read once per block. STAGGER: each block rotates its K-window
// assignment and within-window phase by blk, so concurrent blocks touch
// DIFFERENT W lines at any instant (L2 same-line contention test).
// blocks 0..255: 8 video rows.  blocks 256..415: query row -> eq.
__global__ __launch_bounds__(512) void kNODE(
    const float* __restrict__ video, const float* __restrict__ Wv,
    const float* __restrict__ bvp,
    const float* __restrict__ We, const float* __restrict__ be,
    const float* __restrict__ vmask,
    const int* __restrict__ word_ids, const int* __restrict__ char_ids,
    const float* __restrict__ word_emb, const float* __restrict__ char_emb,
    const float* __restrict__ W_embed, const float* __restrict__ b_embed,
    const float* __restrict__ q_mask,
    const float* __restrict__ Wq, const float* __restrict__ bq,
    const float* __restrict__ Wk, const float* __restrict__ bk,
    const float* __restrict__ Wvv, const float* __restrict__ bval,
    const float* __restrict__ Ws, const float* __restrict__ bs,
    float* __restrict__ q, float* __restrict__ k,
    float* __restrict__ v, float* __restrict__ sk,
    float* __restrict__ eq)
{
  // regions (floats): [0, 8224) Vl staging [8][1028]  (dead after GEMM reads)
  //                   [0,16896) ps partials as float4 [16][8][33]  (union w/ Vl)
  //                   [16896, +1056) hl[8][132]; [17952, +1056) xe[8][132]
  __shared__ __align__(16) float smem_f[19008];
  float4* ps4 = reinterpret_cast<float4*>(smem_f);
  float* hl = smem_f + 16896;
  float* xe = smem_f + 17952;
  const int blk = blockIdx.x, tid = threadIdx.x;
  const float* Wm[4] = {Wq, Wk, Wvv, Ws};
  const float* bm[4] = {bq, bk, bval, bs};
  float* om[4] = {q, k, v, sk};

  if (blk < 256) {
    const int r0 = blk * 8;
    {   // stage 8 video rows into padded Vl
      const float4* src = reinterpret_cast<const float4*>(video + (size_t)r0 * 1024);
      #pragma unroll
      for (int i = 0; i < 4; ++i) {
        const int idx4 = tid + i * 512;
        const int r = idx4 >> 8, f = idx4 & 255;
        *reinterpret_cast<float4*>(&smem_f[r * 1028 + f * 4]) = src[r * 256 + f];
      }
    }
    __syncthreads();
    const int c4 = tid & 31, ks = tid >> 5;     // ks: 16-way K-split
    float4 acc[8];
    // ---- video GEMM: K=1024; STAGGERED window kw and phase kc ----
    #pragma unroll
    for (int r = 0; r < 8; ++r) acc[r] = float4{0.f, 0.f, 0.f, 0.f};
    {
      const int kw = (ks + blk) & 15;           // rotated K-window (bijective)
      const float4* W4 = reinterpret_cast<const float4*>(Wv) + c4;
      for (int kc = 0; kc < 16; ++kc) {
        const int kcr = (kc + blk) & 15;        // rotated within-window phase
        const int k0 = kw * 64 + kcr * 4;
        const float4 w0 = W4[(size_t)(k0 + 0) * 32];
        const float4 w1 = W4[(size_t)(k0 + 1) * 32];
        const float4 w2 = W4[(size_t)(k0 + 2) * 32];
        const float4 w3 = W4[(size_t)(k0 + 3) * 32];
        #pragma unroll
        for (int r = 0; r < 8; ++r) {
          const float4 rv = *reinterpret_cast<const float4*>(&smem_f[r * 1028 + k0]);
          FMA4(acc[r], rv.x, w0); FMA4(acc[r], rv.y, w1);
          FMA4(acc[r], rv.z, w2); FMA4(acc[r], rv.w, w3);
        }
      }
    }
    __syncthreads();                            // Vl reads done -> ps may overwrite
    #pragma unroll
    for (int r = 0; r < 8; ++r) ps4[(ks * 8 + r) * 33 + c4] = acc[r];
    __syncthreads();
    if (tid < 256) {                            // reduce 16 K-splits + bias -> hl
      const int r = tid >> 5, c = tid & 31;
      float4 s = reinterpret_cast<const float4*>(bvp)[c];
      #pragma unroll
      for (int ke = 0; ke < 16; ++ke) {
        const float4 p = ps4[(ke * 8 + r) * 33 + c];
        s.x += p.x; s.y += p.y; s.z += p.z; s.w += p.w;
      }
      *reinterpret_cast<float4*>(&hl[r * 132 + c * 4]) = s;
    }
    __syncthreads();
    // ---- enc GEMM: K=128; staggered window ----
    #pragma unroll
    for (int r = 0; r < 8; ++r) acc[r] = float4{0.f, 0.f, 0.f, 0.f};
    {
      const int kwE = (ks + blk) & 15;
      const float4* We4 = reinterpret_cast<const float4*>(We) + c4;
      #pragma unroll
      for (int kc = 0; kc < 2; ++kc) {
        const int k0 = kwE * 8 + kc * 4;
        const float4 w0 = We4[(size_t)(k0 + 0) * 32];
        const float4 w1 = We4[(size_t)(k0 + 1) * 32];
        const float4 w2 = We4[(size_t)(k0 + 2) * 32];
        const float4 w3 = We4[(size_t)(k0 + 3) * 32];
        #pragma unroll
        for (int r = 0; r < 8; ++r) {
          const float4 rv = *reinterpret_cast<const float4*>(&hl[r * 132 + k0]);
          FMA4(acc[r], rv.x, w0); FMA4(acc[r], rv.y, w1);
          FMA4(acc[r], rv.z, w2); FMA4(acc[r], rv.w, w3);
        }
      }
    }
    #pragma unroll
    for (int r = 0; r < 8; ++r) ps4[(ks * 8 + r) * 33 + c4] = acc[r];
    __syncthreads();
    if (tid < 256) {                            // reduce + bias + relu*mask -> xe
      const int r = tid >> 5, c = tid & 31;
      float4 s = reinterpret_cast<const float4*>(be)[c];
      #pragma unroll
      for (int ke = 0; ke < 16; ++ke) {
        const float4 p = ps4[(ke * 8 + r) * 33 + c];
        s.x += p.x; s.y += p.y; s.z += p.z; s.w += p.w;
      }
      const float mk = vmask[r0 + r];
      s.x = fmaxf(s.x, 0.f) * mk; s.y = fmaxf(s.y, 0.f) * mk;
      s.z = fmaxf(s.z, 0.f) * mk; s.w = fmaxf(s.w, 0.f) * mk;
      *reinterpret_cast<float4*>(&xe[r * 132 + c * 4]) = s;
    }
    __syncthreads();
    // ---- projections: m = ks>>2; staggered keP and phase ----
    const int m = ks >> 2;
    const int keP = ((ks & 3) + blk) & 3;       // rotated K-quarter (bijective)
    #pragma unroll
    for (int r = 0; r < 8; ++r) acc[r] = float4{0.f, 0.f, 0.f, 0.f};
    {
      const float4* Wp4 = reinterpret_cast<const float4*>(Wm[m]) + c4;
      #pragma unroll
      for (int kc = 0; kc < 8; ++kc) {
        const int kcr = (kc + blk) & 7;
        const int k0 = keP * 32 + kcr * 4;
        const float4 w0 = Wp4[(size_t)(k0 + 0) * 32];
        const float4 w1 = Wp4[(size_t)(k0 + 1) * 32];
        const float4 w2 = Wp4[(size_t)(k0 + 2) * 32];
        const float4 w3 = Wp4[(size_t)(k0 + 3) * 32];
        #pragma unroll
        for (int r = 0; r < 8; ++r) {
          const float4 rv = *reinterpret_cast<const float4*>(&xe[r * 132 + k0]);
          FMA4(acc[r], rv.x, w0); FMA4(acc[r], rv.y, w1);
          FMA4(acc[r], rv.z, w2); FMA4(acc[r], rv.w, w3);
        }
      }
    }
    #pragma unroll
    for (int r = 0; r < 8; ++r) ps4[(ks * 8 + r) * 33 + c4] = acc[r];
    __syncthreads();
    #pragma unroll
    for (int it = 0; it < 2; ++it) {            // reduce 4 K-splits per (m,r,c4)
      const int id = tid + it * 512;
      const int mm = id >> 8, r = (id >> 5) & 7, c = id & 31;
      float4 s = reinterpret_cast<const float4*>(bm[mm])[c];
      #pragma unroll
      for (int ke = 0; ke < 4; ++ke) {
        const float4 p = ps4[((mm * 4 + ke) * 8 + r) * 33 + c];
        s.x += p.x; s.y += p.y; s.z += p.z; s.w += p.w;
      }
      const int vr = r0 + r;
      const int node = (vr >> 8) * 257 + 1 + (vr & 255);
      *reinterpret_cast<float4*>(om[mm] + (size_t)node * 128 + 4 * c) = s;
    }
  } else {
    // ---- query row (256 active threads; barriers unconditional) ----
    const int qi = blk - 256;
    const int b = qi / 20, lq = qi - b * 20;
    float* emb = smem_f;          // [352]
    float* ps  = emb + 352;       // [2][128]
    float* hq  = emb + 608;       // [128]
    float* pe  = emb + 736;       // [2][128]
    const int wid = word_ids[b * LQ_ + lq];
    for (int m2 = tid; m2 < 300; m2 += 512) emb[m2] = word_emb[(size_t)wid * 300 + m2];
    if (tid < 50) {
      float s = 0.f;
      #pragma unroll
      for (int l = 0; l < 10; ++l) {
        const int cid = char_ids[(b * LQ_ + lq) * 10 + l];
        s += char_emb[cid * 50 + tid];
      }
      emb[300 + tid] = s * 0.1f;
    }
    __syncthreads();
    const int j = tid & 127, half = tid >> 7;
    if (tid < 256) {
      float a = 0.f;
      const float* Wcol = W_embed + (size_t)(half * 175) * 128 + j;
      const float* eh = emb + half * 175;
      #pragma unroll 5
      for (int m2 = 0; m2 < 175; ++m2) a += eh[m2] * Wcol[(size_t)m2 * 128];
      ps[half * 128 + j] = a;
    }
    __syncthreads();
    if (tid < 128) hq[tid] = ps[tid] + ps[128 + tid] + b_embed[tid];
    __syncthreads();
    if (tid < 256) {
      float e = 0.f;
      #pragma unroll 8
      for (int kk = 0; kk < 64; ++kk)
        e += hq[half * 64 + kk] * We[(half * 64 + kk) * 128 + j];
      pe[half * 128 + j] = e;
    }
    __syncthreads();
    if (tid < 128) {
      float ev = pe[tid] + pe[128 + tid] + be[tid];
      ev = fmaxf(ev, 0.f) * q_mask[b * LQ_ + lq];
      eq[(size_t)qi * 128 + tid] = ev;
    }
  }
}

// ---------------- edge multiplicity (verified round 1) -----------------------
__device__ __forceinline__ float cntf(int dnode, int s) {
  if (dnode == 256) return (s == 0 ? 1.f : 0.f) + (s == 255 ? 1.f : 0.f);
  float c = (s != dnode) ? 1.f : 0.f;          // semantic all-pairs (nodes 0..255)
  if (s == 0) c += 1.f;                        // query->segment
  if (s == dnode - 1) c += 2.f;                // qe chain + temporal h=1 fwd
  if (s == dnode + 1 && dnode <= 254) c += 1.f;// temporal h=1 bwd
  if (s == dnode - 2 && dnode >= 2) c += 1.f;  // temporal h=2 fwd
  if (s == dnode + 2 && dnode <= 253) c += 1.f;// temporal h=2 bwd
  return c;
}

// ---------------- kATTN: single-pass fused exp+PV (proven shape) -------------
__global__ __launch_bounds__(256) void kATTN(
    const float* __restrict__ q, const float* __restrict__ k,
    const float* __restrict__ v, const float* __restrict__ eq,
    const float* __restrict__ Wk, const float* __restrict__ bk,
    const float* __restrict__ Wvv, const float* __restrict__ bval,
    float* __restrict__ npart, float* __restrict__ dpart)
{
  __shared__ float Kl[32][128];
  __shared__ float Vl[32][128];
  __shared__ float m0[128];
  const int d0 = blockIdx.x * 32;
  const int y  = blockIdx.y;
  const int b  = blockIdx.z;
  const int tid = threadIdx.x;
  const int base = b * 257;
  const int s0 = y * 32;
  {
    const float4* ksrc = reinterpret_cast<const float4*>(k + (size_t)(base + s0) * 128);
    const float4* vsrc = reinterpret_cast<const float4*>(v + (size_t)(base + s0) * 128);
    float4* kd = reinterpret_cast<float4*>(Kl);
    float4* vd = reinterpret_cast<float4*>(Vl);
    #pragma unroll
    for (int i = 0; i < 4; ++i) {
      kd[tid + i * 256] = ksrc[tid + i * 256];
      vd[tid + i * 256] = vsrc[tid + i * 256];
    }
  }
  if (y == 0 && tid < 128) {
    float s = 0.f;
    #pragma unroll 4
    for (int lq = 0; lq < LQ_; ++lq) s += eq[((size_t)b * LQ_ + lq) * 128 + tid];
    m0[tid] = s * (1.f / LQ_);
  }
  const int dd = tid >> 3, h = tid & 7;
  const int dnode = d0 + dd + 1;
  const float* qrow = q + (size_t)(base + dnode) * 128 + h * 16;
  const float4 qq0 = *(const float4*)(qrow + 0);
  const float4 qq1 = *(const float4*)(qrow + 4);
  const float4 qq2 = *(const float4*)(qrow + 8);
  const float4 qq3 = *(const float4*)(qrow + 12);
  __syncthreads();
  if (y == 0) {                        // overwrite row 0 with node-0 K/V
    const int j = tid & 127, half = tid >> 7;
    const float* W = half ? Wvv : Wk;
    float acc = half ? bval[j] : bk[j];
    #pragma unroll 8
    for (int kk = 0; kk < 128; ++kk) acc += m0[kk] * W[kk * 128 + j];
    if (half) Vl[0][j] = acc; else Kl[0][j] = acc;
  }
  __syncthreads();

  float den = 0.f;
  float4 o0 = {0,0,0,0}, o1 = {0,0,0,0}, o2 = {0,0,0,0}, o3 = {0,0,0,0};
  #pragma unroll 2
  for (int s = 0; s < 32; ++s) {
    const float* krow = &Kl[s][h * 16];
    const float4 k0 = *(const float4*)(krow + 0);
    const float4 k1 = *(const float4*)(krow + 4);
    const float4 k2 = *(const float4*)(krow + 8);
    const float4 k3 = *(const float4*)(krow + 12);
    float dt = qq0.x*k0.x + qq0.y*k0.y + qq0.z*k0.z + qq0.w*k0.w
             + qq1.x*k1.x + qq1.y*k1.y + qq1.z*k1.z + qq1.w*k1.w
             + qq2.x*k2.x + qq2.y*k2.y + qq2.z*k2.z + qq2.w*k2.w
             + qq3.x*k3.x + qq3.y*k3.y + qq3.z*k3.z + qq3.w*k3.w;
    const float c = cntf(dnode, s0 + s);
    const float pw = c * __expf(dt * 0.25f);
    den += pw;
    const float* vrow = &Vl[s][h * 16];
    const float4 v0 = *(const float4*)(vrow + 0);
    const float4 v1 = *(const float4*)(vrow + 4);
    const float4 v2 = *(const float4*)(vrow + 8);
    const float4 v3 = *(const float4*)(vrow + 12);
    o0.x += pw*v0.x; o0.y += pw*v0.y; o0.z += pw*v0.z; o0.w += pw*v0.w;
    o1.x += pw*v1.x; o1.y += pw*v1.y; o1.z += pw*v1.z; o1.w += pw*v1.w;
    o2.x += pw*v2.x; o2.y += pw*v2.y; o2.z += pw*v2.z; o2.w += pw*v2.w;
    o3.x += pw*v3.x; o3.y += pw*v3.y; o3.z += pw*v3.z; o3.w += pw*v3.w;
  }
  const size_t pb = ((size_t)y * 8 + b) * 256 + d0;
  float* np = npart + (pb + dd) * 128 + h * 16;
  *reinterpret_cast<float4*>(np + 0)  = o0;
  *reinterpret_cast<float4*>(np + 4)  = o1;
  *reinterpret_cast<float4*>(np + 8)  = o2;
  *reinterpret_cast<float4*>(np + 12) = o3;
  dpart[(pb + dd) * 8 + h] = den;
}

// ---------------- kRED: combine 8 partials + skip + start/end logits ---------
__global__ __launch_bounds__(256) void kRED(
    const float* __restrict__ npart, const float* __restrict__ dpart,
    const float* __restrict__ sk,
    const float* __restrict__ W_start, const float* __restrict__ b_start,
    const float* __restrict__ W_end, const float* __restrict__ b_end,
    float* __restrict__ out)
{
  __shared__ float red[16][2][2];
  const int d0 = blockIdx.x * 16;
  const int b = blockIdx.y;
  const int tid = threadIdx.x;
  const int base = b * 257;
  const int jB = tid & 127, shB = tid >> 7;
  const int hB = jB >> 4;
  const float wst = W_start[jB], wen = W_end[jB];
  #pragma unroll
  for (int dd8 = 0; dd8 < 8; ++dd8) {
    const int dd = shB * 8 + dd8;
    const int dst = d0 + dd;
    float num = 0.f, den = 0.f;
    #pragma unroll
    for (int y = 0; y < 8; ++y) {
      const size_t pb = ((size_t)y * 8 + b) * 256 + dst;
      num += npart[pb * 128 + jB];
      den += dpart[pb * 8 + hB];
    }
    const float o = num / (den + 1e-16f) + sk[(size_t)(base + dst + 1) * 128 + jB];
    float psum = o * wst, pesum = o * wen;
    #pragma unroll
    for (int off = 1; off < 64; off <<= 1) {
      psum += __shfl_xor(psum, off);
      pesum += __shfl_xor(pesum, off);
    }
    if ((tid & 63) == 0) { red[dd][jB >> 6][0] = psum; red[dd][jB >> 6][1] = pesum; }
  }
  __syncthreads();
  if (tid < 16) {
    out[b * 256 + d0 + tid]        = red[tid][0][0] + red[tid][1][0] + b_start[0];
    out[2048 + b * 256 + d0 + tid] = red[tid][0][1] + red[tid][1][1] + b_end[0];
  }
}

extern "C" void kernel_launch(void* const* d_in, const int* in_sizes, int n_in,
                              void* d_out, int out_size, void* d_ws, size_t ws_size,
                              hipStream_t stream) {
  const int*   word_ids = (const int*)d_in[0];
  const int*   char_ids = (const int*)d_in[1];
  const float* video    = (const float*)d_in[2];
  const float* v_mask   = (const float*)d_in[3];
  const float* q_mask   = (const float*)d_in[4];
  const float* word_emb = (const float*)d_in[5];
  const float* char_emb = (const float*)d_in[6];
  const float* W_embed  = (const float*)d_in[7];
  const float* b_embed  = (const float*)d_in[8];
  const float* W_vproj  = (const float*)d_in[9];
  const float* b_vproj  = (const float*)d_in[10];
  const float* W_enc    = (const float*)d_in[11];
  const float* b_enc    = (const float*)d_in[12];
  const float* Wq       = (const float*)d_in[13];
  const float* bq       = (const float*)d_in[14];
  const float* Wk       = (const float*)d_in[15];
  const float* bk       = (const float*)d_in[16];
  const float* Wv       = (const float*)d_in[17];
  const float* bv       = (const float*)d_in[18];
  const float* Wskip    = (const float*)d_in[19];
  const float* bskip    = (const float*)d_in[20];
  const float* W_start  = (const float*)d_in[21];
  const float* b_start  = (const float*)d_in[22];
  const float* W_end    = (const float*)d_in[23];
  const float* b_end    = (const float*)d_in[24];

  float* q     = (float*)d_ws;
  float* k     = q  + NN_ * DIM_;
  float* v     = k  + NN_ * DIM_;
  float* sk    = v  + NN_ * DIM_;
  float* eq    = sk + NN_ * DIM_;                    // 160*128
  float* npart = eq + 160 * 128;                     // 8*8*256*128
  float* dpart = npart + (size_t)8 * 8 * 256 * 128;  // 8*8*256*8

  hipLaunchKernelGGL(kNODE, dim3(416), dim3(512), 0, stream,
    video, W_vproj, b_vproj, W_enc, b_enc, v_mask,
    word_ids, char_ids, word_emb, char_emb, W_embed, b_embed, q_mask,
    Wq, bq, Wk, bk, Wv, bv, Wskip, bskip, q, k, v, sk, eq);
  hipLaunchKernelGGL(kATTN, dim3(8, 8, 8), dim3(256), 0, stream,
    q, k, v, eq, Wk, bk, Wv, bv, npart, dpart);
  hipLaunchKernelGGL(kRED, dim3(16, 8), dim3(256), 0, stream,
    npart, dpart, sk, W_start, b_start, W_end, b_end, (float*)d_out);
}

// Round 20
// 58.371 us; speedup vs baseline: 1.2999x; 1.0772x over previous
//
#include <hip/hip_runtime.h>
#include <hip/hip_bf16.h>
#include <math.h>

#define B_ 8
#define T_ 256
#define LQ_ 20
#define LC_ 10
#define DIM_ 128
#define N_ 257            // T+1
#define NN_ (B_*N_)       // 2056

// NOTE: parameter must NOT be named 'w'/'x'/'y'/'z' (R12 preprocessor trap).
#define FMA4(a, s, ww) { (a).x += (s)*(ww).x; (a).y += (s)*(ww).y; (a).z += (s)*(ww).z; (a).w += (s)*(ww).w; }

// ---------------- kNODE: R13-proven node pipeline (60.5 us config) -----------
// 512 thr. Thread = (c4 0..31, ks 0..15); owns all 8 rows -> 32 FMA per
// 16B W-load; W read once per block. K-split partials alias the dead video
// staging buffer (union) -> 76 KB LDS, 2 blocks/CU.
// blocks 0..255: 8 video rows.  blocks 256..415: query row -> eq.
__global__ __launch_bounds__(512) void kNODE(
    const float* __restrict__ video, const float* __restrict__ Wv,
    const float* __restrict__ bvp,
    const float* __restrict__ We, const float* __restrict__ be,
    const float* __restrict__ vmask,
    const int* __restrict__ word_ids, const int* __restrict__ char_ids,
    const float* __restrict__ word_emb, const float* __restrict__ char_emb,
    const float* __restrict__ W_embed, const float* __restrict__ b_embed,
    const float* __restrict__ q_mask,
    const float* __restrict__ Wq, const float* __restrict__ bq,
    const float* __restrict__ Wk, const float* __restrict__ bk,
    const float* __restrict__ Wvv, const float* __restrict__ bval,
    const float* __restrict__ Ws, const float* __restrict__ bs,
    float* __restrict__ q, float* __restrict__ k,
    float* __restrict__ v, float* __restrict__ sk,
    float* __restrict__ eq)
{
  __shared__ __align__(16) float smem_f[19008];
  float4* ps4 = reinterpret_cast<float4*>(smem_f);
  float* hl = smem_f + 16896;
  float* xe = smem_f + 17952;
  const int blk = blockIdx.x, tid = threadIdx.x;
  const float* Wm[4] = {Wq, Wk, Wvv, Ws};
  const float* bm[4] = {bq, bk, bval, bs};
  float* om[4] = {q, k, v, sk};

  if (blk < 256) {
    const int r0 = blk * 8;
    {   // stage 8 video rows into padded Vl
      const float4* src = reinterpret_cast<const float4*>(video + (size_t)r0 * 1024);
      #pragma unroll
      for (int i = 0; i < 4; ++i) {
        const int idx4 = tid + i * 512;
        const int r = idx4 >> 8, f = idx4 & 255;
        *reinterpret_cast<float4*>(&smem_f[r * 1028 + f * 4]) = src[r * 256 + f];
      }
    }
    __syncthreads();
    const int c4 = tid & 31, ks = tid >> 5;     // ks: 16-way K-split
    float4 acc[8];
    #pragma unroll
    for (int r = 0; r < 8; ++r) acc[r] = float4{0.f, 0.f, 0.f, 0.f};
    {
      const float4* W4 = reinterpret_cast<const float4*>(Wv) + c4;
      for (int kc = 0; kc < 16; ++kc) {
        const int k0 = ks * 64 + kc * 4;
        const float4 w0 = W4[(size_t)(k0 + 0) * 32];
        const float4 w1 = W4[(size_t)(k0 + 1) * 32];
        const float4 w2 = W4[(size_t)(k0 + 2) * 32];
        const float4 w3 = W4[(size_t)(k0 + 3) * 32];
        #pragma unroll
        for (int r = 0; r < 8; ++r) {
          const float4 rv = *reinterpret_cast<const float4*>(&smem_f[r * 1028 + k0]);
          FMA4(acc[r], rv.x, w0); FMA4(acc[r], rv.y, w1);
          FMA4(acc[r], rv.z, w2); FMA4(acc[r], rv.w, w3);
        }
      }
    }
    __syncthreads();                            // Vl reads done -> ps may overwrite
    #pragma unroll
    for (int r = 0; r < 8; ++r) ps4[(ks * 8 + r) * 33 + c4] = acc[r];
    __syncthreads();
    if (tid < 256) {                            // reduce 16 K-splits + bias -> hl
      const int r = tid >> 5, c = tid & 31;
      float4 s = reinterpret_cast<const float4*>(bvp)[c];
      #pragma unroll
      for (int ke = 0; ke < 16; ++ke) {
        const float4 p = ps4[(ke * 8 + r) * 33 + c];
        s.x += p.x; s.y += p.y; s.z += p.z; s.w += p.w;
      }
      *reinterpret_cast<float4*>(&hl[r * 132 + c * 4]) = s;
    }
    __syncthreads();
    #pragma unroll
    for (int r = 0; r < 8; ++r) acc[r] = float4{0.f, 0.f, 0.f, 0.f};
    {
      const float4* We4 = reinterpret_cast<const float4*>(We) + c4;
      #pragma unroll
      for (int kc = 0; kc < 2; ++kc) {
        const int k0 = ks * 8 + kc * 4;
        const float4 w0 = We4[(size_t)(k0 + 0) * 32];
        const float4 w1 = We4[(size_t)(k0 + 1) * 32];
        const float4 w2 = We4[(size_t)(k0 + 2) * 32];
        const float4 w3 = We4[(size_t)(k0 + 3) * 32];
        #pragma unroll
        for (int r = 0; r < 8; ++r) {
          const float4 rv = *reinterpret_cast<const float4*>(&hl[r * 132 + k0]);
          FMA4(acc[r], rv.x, w0); FMA4(acc[r], rv.y, w1);
          FMA4(acc[r], rv.z, w2); FMA4(acc[r], rv.w, w3);
        }
      }
    }
    #pragma unroll
    for (int r = 0; r < 8; ++r) ps4[(ks * 8 + r) * 33 + c4] = acc[r];
    __syncthreads();
    if (tid < 256) {                            // reduce + bias + relu*mask -> xe
      const int r = tid >> 5, c = tid & 31;
      float4 s = reinterpret_cast<const float4*>(be)[c];
      #pragma unroll
      for (int ke = 0; ke < 16; ++ke) {
        const float4 p = ps4[(ke * 8 + r) * 33 + c];
        s.x += p.x; s.y += p.y; s.z += p.z; s.w += p.w;
      }
      const float mk = vmask[r0 + r];
      s.x = fmaxf(s.x, 0.f) * mk; s.y = fmaxf(s.y, 0.f) * mk;
      s.z = fmaxf(s.z, 0.f) * mk; s.w = fmaxf(s.w, 0.f) * mk;
      *reinterpret_cast<float4*>(&xe[r * 132 + c * 4]) = s;
    }
    __syncthreads();
    const int m = ks >> 2, keP = ks & 3;
    #pragma unroll
    for (int r = 0; r < 8; ++r) acc[r] = float4{0.f, 0.f, 0.f, 0.f};
    {
      const float4* Wp4 = reinterpret_cast<const float4*>(Wm[m]) + c4;
      #pragma unroll
      for (int kc = 0; kc < 8; ++kc) {
        const int k0 = keP * 32 + kc * 4;
        const float4 w0 = Wp4[(size_t)(k0 + 0) * 32];
        const float4 w1 = Wp4[(size_t)(k0 + 1) * 32];
        const float4 w2 = Wp4[(size_t)(k0 + 2) * 32];
        const float4 w3 = Wp4[(size_t)(k0 + 3) * 32];
        #pragma unroll
        for (int r = 0; r < 8; ++r) {
          const float4 rv = *reinterpret_cast<const float4*>(&xe[r * 132 + k0]);
          FMA4(acc[r], rv.x, w0); FMA4(acc[r], rv.y, w1);
          FMA4(acc[r], rv.z, w2); FMA4(acc[r], rv.w, w3);
        }
      }
    }
    #pragma unroll
    for (int r = 0; r < 8; ++r) ps4[(ks * 8 + r) * 33 + c4] = acc[r];
    __syncthreads();
    #pragma unroll
    for (int it = 0; it < 2; ++it) {            // reduce 4 K-splits per (m,r,c4)
      const int id = tid + it * 512;
      const int mm = id >> 8, r = (id >> 5) & 7, c = id & 31;
      float4 s = reinterpret_cast<const float4*>(bm[mm])[c];
      #pragma unroll
      for (int ke = 0; ke < 4; ++ke) {
        const float4 p = ps4[((mm * 4 + ke) * 8 + r) * 33 + c];
        s.x += p.x; s.y += p.y; s.z += p.z; s.w += p.w;
      }
      const int vr = r0 + r;
      const int node = (vr >> 8) * 257 + 1 + (vr & 255);
      *reinterpret_cast<float4*>(om[mm] + (size_t)node * 128 + 4 * c) = s;
    }
  } else {
    // ---- query row (256 active threads; barriers unconditional) ----
    const int qi = blk - 256;
    const int b = qi / 20, lq = qi - b * 20;
    float* emb = smem_f;          // [352]
    float* ps  = emb + 352;       // [2][128]
    float* hq  = emb + 608;       // [128]
    float* pe  = emb + 736;       // [2][128]
    const int wid = word_ids[b * LQ_ + lq];
    for (int m2 = tid; m2 < 300; m2 += 512) emb[m2] = word_emb[(size_t)wid * 300 + m2];
    if (tid < 50) {
      float s = 0.f;
      #pragma unroll
      for (int l = 0; l < 10; ++l) {
        const int cid = char_ids[(b * LQ_ + lq) * 10 + l];
        s += char_emb[cid * 50 + tid];
      }
      emb[300 + tid] = s * 0.1f;
    }
    __syncthreads();
    const int j = tid & 127, half = tid >> 7;
    if (tid < 256) {
      float a = 0.f;
      const float* Wcol = W_embed + (size_t)(half * 175) * 128 + j;
      const float* eh = emb + half * 175;
      #pragma unroll 5
      for (int m2 = 0; m2 < 175; ++m2) a += eh[m2] * Wcol[(size_t)m2 * 128];
      ps[half * 128 + j] = a;
    }
    __syncthreads();
    if (tid < 128) hq[tid] = ps[tid] + ps[128 + tid] + b_embed[tid];
    __syncthreads();
    if (tid < 256) {
      float e = 0.f;
      #pragma unroll 8
      for (int kk = 0; kk < 64; ++kk)
        e += hq[half * 64 + kk] * We[(half * 64 + kk) * 128 + j];
      pe[half * 128 + j] = e;
    }
    __syncthreads();
    if (tid < 128) {
      float ev = pe[tid] + pe[128 + tid] + be[tid];
      ev = fmaxf(ev, 0.f) * q_mask[b * LQ_ + lq];
      eq[(size_t)qi * 128 + tid] = ev;
    }
  }
}

// ---------------- edge multiplicity (verified round 1) -----------------------
__device__ __forceinline__ float cntf(int dnode, int s) {
  if (dnode == 256) return (s == 0 ? 1.f : 0.f) + (s == 255 ? 1.f : 0.f);
  float c = (s != dnode) ? 1.f : 0.f;          // semantic all-pairs (nodes 0..255)
  if (s == 0) c += 1.f;                        // query->segment
  if (s == dnode - 1) c += 2.f;                // qe chain + temporal h=1 fwd
  if (s == dnode + 1 && dnode <= 254) c += 1.f;// temporal h=1 bwd
  if (s == dnode - 2 && dnode >= 2) c += 1.f;  // temporal h=2 fwd
  if (s == dnode + 2 && dnode <= 253) c += 1.f;// temporal h=2 bwd
  return c;
}

// ---------------- kATTN: scalar-logit attention partials ---------------------
// Algebra: out_start only needs Σ_h (1/den_h)·Σ_s w_s·Vst_h[s] where
// Vst_h[s] = V[s][h16..]·Wst[h16..]. PV phase collapses to 2 FMA/s; partials
// are 3 scalars per (dst,h,chunk). Grid (8,8,8), 256 thr, thread=(dd,h).
__global__ __launch_bounds__(256) void kATTN(
    const float* __restrict__ q, const float* __restrict__ k,
    const float* __restrict__ v, const float* __restrict__ eq,
    const float* __restrict__ Wk, const float* __restrict__ bk,
    const float* __restrict__ Wvv, const float* __restrict__ bval,
    const float* __restrict__ W_start, const float* __restrict__ W_end,
    float* __restrict__ nst_p, float* __restrict__ nen_p,
    float* __restrict__ den_p)
{
  __shared__ float Kl[32][128];
  __shared__ float Vl[32][128];
  __shared__ float m0[128];
  __shared__ float vstl[32][8];
  __shared__ float venl[32][8];
  const int d0 = blockIdx.x * 32;
  const int y  = blockIdx.y;
  const int b  = blockIdx.z;
  const int tid = threadIdx.x;
  const int base = b * 257;
  const int s0 = y * 32;
  {
    const float4* ksrc = reinterpret_cast<const float4*>(k + (size_t)(base + s0) * 128);
    const float4* vsrc = reinterpret_cast<const float4*>(v + (size_t)(base + s0) * 128);
    float4* kd = reinterpret_cast<float4*>(Kl);
    float4* vd = reinterpret_cast<float4*>(Vl);
    #pragma unroll
    for (int i = 0; i < 4; ++i) {
      kd[tid + i * 256] = ksrc[tid + i * 256];
      vd[tid + i * 256] = vsrc[tid + i * 256];
    }
  }
  if (y == 0 && tid < 128) {
    float s = 0.f;
    #pragma unroll 4
    for (int lq = 0; lq < LQ_; ++lq) s += eq[((size_t)b * LQ_ + lq) * 128 + tid];
    m0[tid] = s * (1.f / LQ_);
  }
  const int dd = tid >> 3, h = tid & 7;
  const int dnode = d0 + dd + 1;
  const float* qrow = q + (size_t)(base + dnode) * 128 + h * 16;
  const float4 qq0 = *(const float4*)(qrow + 0);
  const float4 qq1 = *(const float4*)(qrow + 4);
  const float4 qq2 = *(const float4*)(qrow + 8);
  const float4 qq3 = *(const float4*)(qrow + 12);
  __syncthreads();
  if (y == 0) {                        // overwrite row 0 with node-0 K/V
    const int j = tid & 127, half = tid >> 7;
    const float* W = half ? Wvv : Wk;
    float acc = half ? bval[j] : bk[j];
    #pragma unroll 8
    for (int kk = 0; kk < 128; ++kk) acc += m0[kk] * W[kk * 128 + j];
    if (half) Vl[0][j] = acc; else Kl[0][j] = acc;
  }
  __syncthreads();
  {                                    // per-(s,h) V·Wst / V·Wen scalars
    const int sv = tid >> 3, hv = tid & 7;
    const float* vr = &Vl[sv][hv * 16];
    const float* wst = W_start + hv * 16;
    const float* wen = W_end + hv * 16;
    float a = 0.f, e = 0.f;
    #pragma unroll
    for (int i = 0; i < 16; ++i) { a += vr[i] * wst[i]; e += vr[i] * wen[i]; }
    vstl[sv][hv] = a; venl[sv][hv] = e;
  }
  __syncthreads();

  float den = 0.f, nst = 0.f, nen = 0.f;
  #pragma unroll 4
  for (int s = 0; s < 32; ++s) {
    const float* krow = &Kl[s][h * 16];
    const float4 k0 = *(const float4*)(krow + 0);
    const float4 k1 = *(const float4*)(krow + 4);
    const float4 k2 = *(const float4*)(krow + 8);
    const float4 k3 = *(const float4*)(krow + 12);
    float dt = qq0.x*k0.x + qq0.y*k0.y + qq0.z*k0.z + qq0.w*k0.w
             + qq1.x*k1.x + qq1.y*k1.y + qq1.z*k1.z + qq1.w*k1.w
             + qq2.x*k2.x + qq2.y*k2.y + qq2.z*k2.z + qq2.w*k2.w
             + qq3.x*k3.x + qq3.y*k3.y + qq3.z*k3.z + qq3.w*k3.w;
    const float c = cntf(dnode, s0 + s);
    const float pw = c * __expf(dt * 0.25f);
    den += pw;
    nst += pw * vstl[s][h];
    nen += pw * venl[s][h];
  }
  const size_t pb = (((size_t)y * 8 + b) * 256 + d0 + dd) * 8 + h;
  nst_p[pb] = nst; nen_p[pb] = nen; den_p[pb] = den;
}

// ---------------- kRED: scalar combine + skip-dot + logits -------------------
__global__ __launch_bounds__(256) void kRED(
    const float* __restrict__ nst_p, const float* __restrict__ nen_p,
    const float* __restrict__ den_p, const float* __restrict__ sk,
    const float* __restrict__ W_start, const float* __restrict__ b_start,
    const float* __restrict__ W_end, const float* __restrict__ b_end,
    float* __restrict__ out)
{
  __shared__ float attst[16], atten[16];
  __shared__ float red[16][2][2];
  const int d0 = blockIdx.x * 16;
  const int b = blockIdx.y;
  const int tid = threadIdx.x;
  const int base = b * 257;
  if (tid < 128) {                     // (dd 0..15, h 0..7): sum chunks, /den
    const int dd = tid >> 3, h = tid & 7;
    const int dst = d0 + dd;
    float den = 0.f, nst = 0.f, nen = 0.f;
    #pragma unroll
    for (int y = 0; y < 8; ++y) {
      const size_t pb = (((size_t)y * 8 + b) * 256 + dst) * 8 + h;
      nst += nst_p[pb]; nen += nen_p[pb]; den += den_p[pb];
    }
    float rst = nst / (den + 1e-16f);
    float ren = nen / (den + 1e-16f);
    #pragma unroll
    for (int off = 1; off < 8; off <<= 1) {
      rst += __shfl_xor(rst, off);
      ren += __shfl_xor(ren, off);
    }
    if (h == 0) { attst[dd] = rst; atten[dd] = ren; }
  }
  __syncthreads();
  const int jB = tid & 127, shB = tid >> 7;
  const float wst = W_start[jB], wen = W_end[jB];
  #pragma unroll
  for (int dd8 = 0; dd8 < 8; ++dd8) {
    const int dd = shB * 8 + dd8;
    const int dst = d0 + dd;
    const float o = sk[(size_t)(base + dst + 1) * 128 + jB];
    float psum = o * wst, pesum = o * wen;
    #pragma unroll
    for (int off = 1; off < 64; off <<= 1) {
      psum += __shfl_xor(psum, off);
      pesum += __shfl_xor(pesum, off);
    }
    if ((tid & 63) == 0) { red[dd][jB >> 6][0] = psum; red[dd][jB >> 6][1] = pesum; }
  }
  __syncthreads();
  if (tid < 16) {
    out[b * 256 + d0 + tid]        = red[tid][0][0] + red[tid][1][0] + attst[tid] + b_start[0];
    out[2048 + b * 256 + d0 + tid] = red[tid][0][1] + red[tid][1][1] + atten[tid] + b_end[0];
  }
}

extern "C" void kernel_launch(void* const* d_in, const int* in_sizes, int n_in,
                              void* d_out, int out_size, void* d_ws, size_t ws_size,
                              hipStream_t stream) {
  const int*   word_ids = (const int*)d_in[0];
  const int*   char_ids = (const int*)d_in[1];
  const float* video    = (const float*)d_in[2];
  const float* v_mask   = (const float*)d_in[3];
  const float* q_mask   = (const float*)d_in[4];
  const float* word_emb = (const float*)d_in[5];
  const float* char_emb = (const float*)d_in[6];
  const float* W_embed  = (const float*)d_in[7];
  const float* b_embed  = (const float*)d_in[8];
  const float* W_vproj  = (const float*)d_in[9];
  const float* b_vproj  = (const float*)d_in[10];
  const float* W_enc    = (const float*)d_in[11];
  const float* b_enc    = (const float*)d_in[12];
  const float* Wq       = (const float*)d_in[13];
  const float* bq       = (const float*)d_in[14];
  const float* Wk       = (const float*)d_in[15];
  const float* bk       = (const float*)d_in[16];
  const float* Wv       = (const float*)d_in[17];
  const float* bv       = (const float*)d_in[18];
  const float* Wskip    = (const float*)d_in[19];
  const float* bskip    = (const float*)d_in[20];
  const float* W_start  = (const float*)d_in[21];
  const float* b_start  = (const float*)d_in[22];
  const float* W_end    = (const float*)d_in[23];
  const float* b_end    = (const float*)d_in[24];

  float* q     = (float*)d_ws;
  float* k     = q  + NN_ * DIM_;
  float* v     = k  + NN_ * DIM_;
  float* sk    = v  + NN_ * DIM_;
  float* eq    = sk + NN_ * DIM_;                    // 160*128
  float* nst_p = eq + 160 * 128;                     // 8*8*256*8 = 128K floats
  float* nen_p = nst_p + 131072;
  float* den_p = nen_p + 131072;

  hipLaunchKernelGGL(kNODE, dim3(416), dim3(512), 0, stream,
    video, W_vproj, b_vproj, W_enc, b_enc, v_mask,
    word_ids, char_ids, word_emb, char_emb, W_embed, b_embed, q_mask,
    Wq, bq, Wk, bk, Wv, bv, Wskip, bskip, q, k, v, sk, eq);
  hipLaunchKernelGGL(kATTN, dim3(8, 8, 8), dim3(256), 0, stream,
    q, k, v, eq, Wk, bk, Wv, bv, W_start, W_end, nst_p, nen_p, den_p);
  hipLaunchKernelGGL(kRED, dim3(16, 8), dim3(256), 0, stream,
    nst_p, nen_p, den_p, sk, W_start, b_start, W_end, b_end, (float*)d_out);
}